// Round 9
// baseline (107.766 us; speedup 1.0000x reference)
//
#include <hip/hip_runtime.h>

#define Bn 16
#define Cn 256
#define HWn 9216
#define Pn 64
#define HEADSn 4
#define Gn 2304
#define STILE 64
#define TILES_PER_B (HWn / STILE)    // 144
#define NTILE (Bn * TILES_PER_B)     // 2304
#define CHUNK 9                      // tiles per persistent block
#define NBLK (NTILE / CHUNK)         // 256 blocks, 1 per CU

typedef float f32x4 __attribute__((ext_vector_type(4)));
typedef short short4v __attribute__((ext_vector_type(4)));
typedef short short8 __attribute__((ext_vector_type(8)));

static __device__ __forceinline__ unsigned short f2bf(float f) {
    unsigned int b = __builtin_bit_cast(unsigned int, f);
    unsigned int r = b + 0x7FFFu + ((b >> 16) & 1u);   // RNE
    return (unsigned short)(r >> 16);
}
static __device__ __forceinline__ float bf2f(unsigned short u) {
    unsigned int b = ((unsigned int)u) << 16;
    return __builtin_bit_cast(float, b);
}
static __device__ __forceinline__ void gload_lds16(const void* g, void* l) {
    __builtin_amdgcn_global_load_lds((const __attribute__((address_space(1))) void*)g,
                                     (__attribute__((address_space(3))) void*)l, 16, 0, 0);
}

// ---- K0: w1 -> bf16 with BN scale folded per row; bc vector ----
__global__ __launch_bounds__(256)
void k0_prep(const float* __restrict__ w1, const float* __restrict__ b1,
             const float* __restrict__ gamma, const float* __restrict__ beta,
             const float* __restrict__ mean, const float* __restrict__ var,
             float* __restrict__ bcv, short* __restrict__ w1b)
{
    const int gid = blockIdx.x * 256 + threadIdx.x;
    if (gid < 2048) {                       // 2048 granules of 8 floats
        const int row = gid >> 5;
        const float s = gamma[row] * rsqrtf(var[row] + 1e-5f);
        const float* p = w1 + gid * 8;
        short8 v;
        #pragma unroll
        for (int j = 0; j < 8; ++j) v[j] = (short)f2bf(p[j] * s);
        *reinterpret_cast<short8*>(&w1b[gid * 8]) = v;
    }
    if (gid < Pn) {
        const float s = gamma[gid] * rsqrtf(var[gid] + 1e-5f);
        bcv[gid] = (b1[gid] - mean[gid]) * s + beta[gid];
    }
}

// ---- K1: persistent; A-frags in registers; x f32 via global_load_lds, swizzled ----
// LDS word for element (k,s): k*64 + (s ^ (((k>>3)&3)<<4))  -> 2-way conflict B-reads
__global__ __launch_bounds__(256, 1)
void k1_gemm(const float* __restrict__ x, const short* __restrict__ w1b,
             const float* __restrict__ bcv, const float* __restrict__ wm,
             float* __restrict__ hmp, short* __restrict__ hg)
{
    __shared__ float xl[2][Cn * STILE];   // 2 x 64 KB f32, word-swizzled
    __shared__ float hml[4][Pn];

    const int pid  = blockIdx.x;            // 0..255
    const int b    = pid >> 4;
    const int t0b  = (pid & 15) * CHUNK;    // first tile within batch (never straddles head)
    const int t    = threadIdx.x;
    const int lane = t & 63;
    const int wv   = t >> 6;
    const int wvu  = __builtin_amdgcn_readfirstlane(wv);
    const int g    = lane >> 4;
    const int m16  = lane & 15;
    const int sbase = wv * 16 + m16;

    // ---- A-fragments (BN-scale folded) once into registers: 128 VGPR ----
    short8 af[4][8];
    #pragma unroll
    for (int rt = 0; rt < 4; ++rt)
        #pragma unroll
        for (int ks = 0; ks < 8; ++ks)
            af[rt][ks] = *reinterpret_cast<const short8*>(
                w1b + (rt * 16 + m16) * Cn + ks * 32 + g * 8);

    float bc[4][4];
    #pragma unroll
    for (int rt = 0; rt < 4; ++rt)
        #pragma unroll
        for (int r = 0; r < 4; ++r) bc[rt][r] = bcv[rt * 16 + g * 4 + r];

    float hmacc[4][4];
    #pragma unroll
    for (int rt = 0; rt < 4; ++rt)
        #pragma unroll
        for (int r = 0; r < 4; ++r) hmacc[rt][r] = 0.f;

    const float* xbb = x + (size_t)b * Cn * HWn;

    // stage tile -> xl[buf]: 16 x 1KB wave-uniform chunks; source pre-inverse-swizzled
    #define STAGE(buf, tile)                                                     \
        do {                                                                     \
            const int _s0 = (tile) * STILE;                                      \
            _Pragma("unroll")                                                    \
            for (int i = 0; i < 16; ++i) {                                       \
                const int cbase = wvu * 64 + i * 4;                              \
                const int c     = cbase + g;                                     \
                const int gc    = (c >> 3) & 3;                                  \
                const int soff  = (m16 * 4) ^ (gc << 4);                         \
                gload_lds16(xbb + (size_t)c * HWn + _s0 + soff,                  \
                            &xl[buf][cbase * 64]);                               \
            }                                                                    \
        } while (0)

    STAGE(0, t0b);
    __syncthreads();

    int cur = 0;
    for (int it = 0; it < CHUNK; ++it) {
        if (it + 1 < CHUNK) STAGE(cur ^ 1, t0b + it + 1);

        const int s0 = (t0b + it) * STILE;
        const float* xc = xl[cur];
        const int srd = sbase ^ (g << 4);          // swizzled s-offset for this lane

        f32x4 acc[4] = { {0,0,0,0}, {0,0,0,0}, {0,0,0,0}, {0,0,0,0} };
        #pragma unroll
        for (int ks = 0; ks < 8; ++ks) {
            short8 bf;
            #pragma unroll
            for (int j = 0; j < 8; ++j) {
                const int k = ks * 32 + g * 8 + j;
                bf[j] = (short)f2bf(xc[k * 64 + srd]);
            }
            #pragma unroll
            for (int rt = 0; rt < 4; ++rt)
                acc[rt] = __builtin_amdgcn_mfma_f32_16x16x32_bf16(af[rt][ks], bf, acc[rt], 0, 0, 0);
        }

        // ---- bias + ReLU, hm register-accumulate, direct h store ----
        const float wmv = wm[s0 + sbase];
        short* hrow = hg + ((size_t)b * HWn + s0 + sbase) * Pn;
        #pragma unroll
        for (int rt = 0; rt < 4; ++rt) {
            short4v hv;
            #pragma unroll
            for (int r = 0; r < 4; ++r) {
                float h = acc[rt][r] + bc[rt][r];
                h = h > 0.f ? h : 0.f;
                hmacc[rt][r] = fmaf(h, wmv, hmacc[rt][r]);
                hv[r] = (short)f2bf(h);
            }
            *reinterpret_cast<short4v*>(hrow + rt * 16 + g * 4) = hv;
        }

        __syncthreads();     // drains stage loads (vmcnt 0) + orders buffer reuse
        cur ^= 1;
    }

    // ---- final hm reduce: shfl over 16 s-columns, combine 4 waves in LDS ----
    #pragma unroll
    for (int rt = 0; rt < 4; ++rt)
        #pragma unroll
        for (int r = 0; r < 4; ++r) {
            float v = hmacc[rt][r];
            v += __shfl_xor(v, 1); v += __shfl_xor(v, 2);
            v += __shfl_xor(v, 4); v += __shfl_xor(v, 8);
            hmacc[rt][r] = v;
        }
    if (m16 == 0) {
        #pragma unroll
        for (int rt = 0; rt < 4; ++rt) {
            f32x4 hv = { hmacc[rt][0], hmacc[rt][1], hmacc[rt][2], hmacc[rt][3] };
            *reinterpret_cast<f32x4*>(&hml[wv][rt * 16 + g * 4]) = hv;
        }
    }
    __syncthreads();
    if (t < Pn) hmp[pid * Pn + t] = hml[0][t] + hml[1][t] + hml[2][t] + hml[3][t];
}

// ---- K2: reduce 4 block-partials -> logits -> softmax -> wmix/bmix ----
__global__ __launch_bounds__(256)
void k2_mask(const float* __restrict__ hmp, const float* __restrict__ w2,
             const float* __restrict__ b2, const float* __restrict__ wm,
             float* __restrict__ wmix, float* __restrict__ bmix)
{
    __shared__ float hms[Pn];
    __shared__ float masks[Cn];
    __shared__ float red[4];
    __shared__ float part[4][Pn];

    const int bh = blockIdx.x;
    const int head = bh & (HEADSn - 1);
    const int t = threadIdx.x;
    const int l = t & 63;
    const int wv = t >> 6;

    // blocks bh*4 .. bh*4+3 hold this (b,head)'s partials
    {
        const int p = t & 63, q = t >> 6;
        part[q][p] = hmp[(bh * 4 + q) * Pn + p];
    }
    __syncthreads();
    if (t < Pn) hms[t] = part[0][t] + part[1][t] + part[2][t] + part[3][t];
    __syncthreads();

    // wmsum over this head's group
    float wsum = 0.f;
    for (int i = t; i < Gn; i += 256) wsum += wm[head * Gn + i];
    #pragma unroll
    for (int d = 1; d < 64; d <<= 1) wsum += __shfl_xor(wsum, d);
    if (l == 0) red[wv] = wsum;
    __syncthreads();
    wsum = red[0] + red[1] + red[2] + red[3];

    // logits[c] = sum_k w2[c,k]*hm[k] + b2[c]*wsum
    float lg = 0.f;
    #pragma unroll
    for (int k = 0; k < Pn; ++k) lg = fmaf(w2[t * Pn + k], hms[k], lg);
    lg = fmaf(b2[t], wsum, lg);

    // softmax over 256 channels
    float mx = lg;
    #pragma unroll
    for (int d = 1; d < 64; d <<= 1) mx = fmaxf(mx, __shfl_xor(mx, d));
    __syncthreads();
    if (l == 0) red[wv] = mx;
    __syncthreads();
    mx = fmaxf(fmaxf(red[0], red[1]), fmaxf(red[2], red[3]));
    const float ev = __expf(lg - mx);
    float sm = ev;
    #pragma unroll
    for (int d = 1; d < 64; d <<= 1) sm += __shfl_xor(sm, d);
    __syncthreads();
    if (l == 0) red[wv] = sm;
    __syncthreads();
    sm = red[0] + red[1] + red[2] + red[3];
    masks[t] = ev / sm;
    __syncthreads();

    // wmix[k] = sum_c mask[c]*w2[c,k]
    {
        const int k = t & (Pn - 1);
        const int q = t >> 6;
        float wp = 0.f;
        #pragma unroll
        for (int i = 0; i < 64; ++i) {
            const int c = q * 64 + i;
            wp = fmaf(masks[c], w2[c * Pn + k], wp);
        }
        part[q][k] = wp;
    }
    __syncthreads();
    if (t < Pn) wmix[bh * Pn + t] = part[0][t] + part[1][t] + part[2][t] + part[3][t];

    // bmix = sum_c mask[c]*b2[c]
    float bp = masks[t] * b2[t];
    #pragma unroll
    for (int d = 1; d < 64; d <<= 1) bp += __shfl_xor(bp, d);
    __syncthreads();
    if (l == 0) red[wv] = bp;
    __syncthreads();
    if (t == 0) bmix[bh] = red[0] + red[1] + red[2] + red[3];
}

// ---- K3: pure streaming: ctx[s] = wmix . h[s,:]; out = x + ctx ----
__global__ __launch_bounds__(256)
void k3_stream(const float* __restrict__ x, const short* __restrict__ hg,
               const float* __restrict__ wmix, const float* __restrict__ bmix,
               float* __restrict__ out)
{
    __shared__ float ctxl[STILE];

    const int bid  = blockIdx.x;
    const int b    = bid / TILES_PER_B;
    const int tile = bid % TILES_PER_B;
    const int s0   = tile * STILE;
    const int head = s0 / Gn;
    const int bh   = b * HEADSn + head;
    const int t    = threadIdx.x;

    if (t < STILE) {
        const short* hr = hg + ((size_t)b * HWn + s0 + t) * Pn;   // dense 128 B/lane
        const float* wmx = wmix + bh * Pn;
        float acc = 0.f;
        #pragma unroll
        for (int i = 0; i < 8; ++i) {
            const short8 v = *reinterpret_cast<const short8*>(hr + i * 8);
            const f32x4 w0 = *reinterpret_cast<const f32x4*>(wmx + i * 8);
            const f32x4 w1v = *reinterpret_cast<const f32x4*>(wmx + i * 8 + 4);
            #pragma unroll
            for (int j = 0; j < 4; ++j) {
                acc = fmaf(bf2f((unsigned short)v[j]), w0[j], acc);
                acc = fmaf(bf2f((unsigned short)v[4 + j]), w1v[j], acc);
            }
        }
        ctxl[t] = acc + bmix[bh];
    }
    __syncthreads();

    const int c0 = t >> 4;
    const int s4 = t & 15;
    const f32x4 cv = *reinterpret_cast<const f32x4*>(&ctxl[s4 * 4]);
    const float* xb = x + (size_t)b * Cn * HWn + s0 + s4 * 4;
    float* ob = out + (size_t)b * Cn * HWn + s0 + s4 * 4;
    #pragma unroll
    for (int i = 0; i < 16; ++i) {
        const size_t off = (size_t)(c0 + 16 * i) * HWn;
        *reinterpret_cast<f32x4*>(ob + off) =
            *reinterpret_cast<const f32x4*>(xb + off) + cv;
    }
}

extern "C" void kernel_launch(void* const* d_in, const int* in_sizes, int n_in,
                              void* d_out, int out_size, void* d_ws, size_t ws_size,
                              hipStream_t stream)
{
    (void)in_sizes; (void)n_in; (void)out_size; (void)ws_size;
    const float* x     = (const float*)d_in[0];
    const float* w1    = (const float*)d_in[1];
    const float* b1    = (const float*)d_in[2];
    const float* gamma = (const float*)d_in[3];
    const float* beta  = (const float*)d_in[4];
    const float* mean  = (const float*)d_in[5];
    const float* var   = (const float*)d_in[6];
    const float* w2    = (const float*)d_in[7];
    const float* b2    = (const float*)d_in[8];
    const float* wm    = (const float*)d_in[9];
    // d_in[10] = bm: constant over softmax axis -> dropped

    float* out  = (float*)d_out;
    float* wsf  = (float*)d_ws;
    float* hmp  = wsf;                            // [256*64] f32 block partials
    float* wmix = hmp + NBLK * Pn;                // [64*64]
    float* bmix = wmix + Bn * HEADSn * Pn;        // [64]
    float* bcv  = bmix + 64;                      // [64]
    short* w1b  = (short*)(bcv + 64);             // [64*256] bf16, BN-scale folded
    short* hg   = w1b + Pn * Cn;                  // [16*9216*64] bf16 (16B-aligned)

    k0_prep<<<dim3(8), dim3(256), 0, stream>>>(w1, b1, gamma, beta, mean, var, bcv, w1b);
    k1_gemm<<<dim3(NBLK), dim3(256), 0, stream>>>(x, w1b, bcv, wm, hmp, hg);
    k2_mask<<<dim3(Bn * HEADSn), dim3(256), 0, stream>>>(hmp, w2, b2, wm, wmix, bmix);
    k3_stream<<<dim3(NTILE), dim3(256), 0, stream>>>(x, hg, wmix, bmix, out);
}

// Round 10
// 101.172 us; speedup vs baseline: 1.0652x; 1.0652x over previous
//
#include <hip/hip_runtime.h>

#define Bn 16
#define Cn 256
#define HWn 9216
#define Pn 64
#define HEADSn 4
#define Gn 2304
#define STILE 64
#define TILES_PER_B (HWn / STILE)    // 144
#define NTILE (Bn * TILES_PER_B)     // 2304 (k3 grid)
#define T32_PER_B 288                // 32-col tiles per batch
#define NBLK1 (Bn * T32_PER_B)       // 4608 k1 blocks

typedef float f32x4 __attribute__((ext_vector_type(4)));
typedef short short4v __attribute__((ext_vector_type(4)));
typedef short short8 __attribute__((ext_vector_type(8)));
typedef unsigned int uint2v __attribute__((ext_vector_type(2)));

static __device__ __forceinline__ unsigned short f2bf(float f) {
    unsigned int b = __builtin_bit_cast(unsigned int, f);
    unsigned int r = b + 0x7FFFu + ((b >> 16) & 1u);   // RNE
    return (unsigned short)(r >> 16);
}
static __device__ __forceinline__ float bf2f(unsigned short u) {
    unsigned int b = ((unsigned int)u) << 16;
    return __builtin_bit_cast(float, b);
}
static __device__ __forceinline__ unsigned int cvtpk(float a, float b) {
    unsigned int r;
    asm("v_cvt_pk_bf16_f32 %0, %1, %2" : "=v"(r) : "v"(a), "v"(b));
    return r;
}

// ---- K0: w1 -> bf16 with BN scale folded per row; bc vector ----
__global__ __launch_bounds__(256)
void k0_prep(const float* __restrict__ w1, const float* __restrict__ b1,
             const float* __restrict__ gamma, const float* __restrict__ beta,
             const float* __restrict__ mean, const float* __restrict__ var,
             float* __restrict__ bcv, short* __restrict__ w1b)
{
    const int gid = blockIdx.x * 256 + threadIdx.x;
    if (gid < 2048) {                       // 2048 granules of 8 floats
        const int row = gid >> 5;
        const float s = gamma[row] * rsqrtf(var[row] + 1e-5f);
        const float* p = w1 + gid * 8;
        short8 v;
        #pragma unroll
        for (int j = 0; j < 8; ++j) v[j] = (short)f2bf(p[j] * s);
        *reinterpret_cast<short8*>(&w1b[gid * 8]) = v;
    }
    if (gid < Pn) {
        const float s = gamma[gid] * rsqrtf(var[gid] + 1e-5f);
        bcv[gid] = (b1[gid] - mean[gid]) * s + beta[gid];
    }
}

// ---- K1: 128-thread blocks, 32-col tiles, A-in-regs, <=128 VGPR, 16 waves/CU ----
// LDS swizzle: elem (k, s in 0..31) -> byte k*64 + (((s>>3) ^ f(k))*16) + (s&7)*2,
// f(k) = (k ^ (k>>2)) & 3
__global__ __launch_bounds__(128, 4)
void k1_gemm(const float* __restrict__ x, const short* __restrict__ w1b,
             const float* __restrict__ bcv, const float* __restrict__ wm,
             float* __restrict__ hmp, short* __restrict__ hg)
{
    __shared__ short xl[Cn * 32];          // 16 KB bf16, swizzled

    const int bid  = blockIdx.x;
    const int b    = bid / T32_PER_B;
    const int t32  = bid % T32_PER_B;
    const int s0   = t32 * 32;
    const int t    = threadIdx.x;
    const int lane = t & 63;
    const int wv   = t >> 6;               // 0..1, owns p in [wv*32, wv*32+32)
    const int g    = lane >> 4;
    const int m16  = lane & 15;

    // ---- A-fragments (BN-scale folded) into registers: 64 VGPR ----
    short8 af[2][8];
    #pragma unroll
    for (int rt = 0; rt < 2; ++rt)
        #pragma unroll
        for (int ks = 0; ks < 8; ++ks)
            af[rt][ks] = *reinterpret_cast<const short8*>(
                w1b + (wv * 32 + rt * 16 + m16) * Cn + ks * 32 + g * 8);

    float bc[2][4];
    #pragma unroll
    for (int rt = 0; rt < 2; ++rt)
        #pragma unroll
        for (int r = 0; r < 4; ++r) bc[rt][r] = bcv[wv * 32 + rt * 16 + g * 4 + r];

    // ---- stage x tile: thread (krow=t>>3, chk=t&7); coalesced 128B per 8 lanes ----
    const int krow = t >> 3;
    const int chk  = t & 7;
    const float* xb = x + (size_t)b * Cn * HWn + s0 + chk * 4;
    #pragma unroll
    for (int i = 0; i < 16; ++i) {
        const int k = i * 16 + krow;
        const f32x4 v = *reinterpret_cast<const f32x4*>(xb + (size_t)k * HWn);
        uint2v pk;
        pk[0] = cvtpk(v[0], v[1]);
        pk[1] = cvtpk(v[2], v[3]);
        const int f    = (k ^ (k >> 2)) & 3;
        const int byte = k * 64 + (((chk >> 1) ^ f) * 16) + (chk & 1) * 8;
        *reinterpret_cast<uint2v*>(reinterpret_cast<char*>(xl) + byte) = pk;
    }
    __syncthreads();

    // ---- GEMM1: 8 ks x { 2 cg x (8 bf16 reads + 2 MFMA) } ----
    f32x4 acc[2][2] = { { {0,0,0,0}, {0,0,0,0} }, { {0,0,0,0}, {0,0,0,0} } };
    #pragma unroll
    for (int ks = 0; ks < 8; ++ks) {
        #pragma unroll
        for (int cg = 0; cg < 2; ++cg) {
            short8 bf;
            #pragma unroll
            for (int j = 0; j < 8; ++j) {
                const int k    = ks * 32 + g * 8 + j;
                const int f    = (k ^ (k >> 2)) & 3;
                const int byte = k * 64 + ((((cg * 2) + (m16 >> 3)) ^ f) * 16) + (m16 & 7) * 2;
                bf[j] = *reinterpret_cast<const short*>(
                    reinterpret_cast<const char*>(xl) + byte);
            }
            acc[cg][0] = __builtin_amdgcn_mfma_f32_16x16x32_bf16(af[0][ks], bf, acc[cg][0], 0, 0, 0);
            acc[cg][1] = __builtin_amdgcn_mfma_f32_16x16x32_bf16(af[1][ks], bf, acc[cg][1], 0, 0, 0);
        }
    }

    // ---- bias + ReLU + h store [s][p] + hm register accumulate ----
    const float wmv0 = wm[s0 + m16];
    const float wmv1 = wm[s0 + 16 + m16];
    float hmacc[2][4];
    #pragma unroll
    for (int rt = 0; rt < 2; ++rt)
        #pragma unroll
        for (int r = 0; r < 4; ++r) hmacc[rt][r] = 0.f;

    #pragma unroll
    for (int cg = 0; cg < 2; ++cg) {
        const float wmv = cg ? wmv1 : wmv0;
        short* hrow = hg + ((size_t)b * HWn + s0 + cg * 16 + m16) * Pn + wv * 32;
        #pragma unroll
        for (int rt = 0; rt < 2; ++rt) {
            float h[4];
            #pragma unroll
            for (int r = 0; r < 4; ++r) {
                float hv = acc[cg][rt][r] + bc[rt][r];
                hv = hv > 0.f ? hv : 0.f;
                hmacc[rt][r] = fmaf(hv, wmv, hmacc[rt][r]);
                h[r] = hv;
            }
            uint2v pk;
            pk[0] = cvtpk(h[0], h[1]);
            pk[1] = cvtpk(h[2], h[3]);
            *reinterpret_cast<uint2v*>(hrow + rt * 16 + g * 4) = pk;
        }
    }

    // ---- hm partial: reduce over the 16 s-columns (shfl), store per-block ----
    #pragma unroll
    for (int rt = 0; rt < 2; ++rt)
        #pragma unroll
        for (int r = 0; r < 4; ++r) {
            float v = hmacc[rt][r];
            v += __shfl_xor(v, 1); v += __shfl_xor(v, 2);
            v += __shfl_xor(v, 4); v += __shfl_xor(v, 8);
            hmacc[rt][r] = v;
        }
    if (m16 == 0) {
        #pragma unroll
        for (int rt = 0; rt < 2; ++rt)
            #pragma unroll
            for (int r = 0; r < 4; ++r)
                hmp[bid * Pn + wv * 32 + rt * 16 + g * 4 + r] = hmacc[rt][r];
    }
}

// ---- K2: reduce 72 tile-partials -> logits -> softmax -> wmix/bmix ----
__global__ __launch_bounds__(256)
void k2_mask(const float* __restrict__ hmp, const float* __restrict__ w2,
             const float* __restrict__ b2, const float* __restrict__ wm,
             float* __restrict__ wmix, float* __restrict__ bmix)
{
    __shared__ float hms[Pn];
    __shared__ float masks[Cn];
    __shared__ float red[4];
    __shared__ float part[4][Pn];

    const int bh = blockIdx.x;
    const int head = bh & (HEADSn - 1);
    const int t = threadIdx.x;
    const int l = t & 63;
    const int wv = t >> 6;

    // this (b,head)'s partials: blocks (b*288 + head*72) .. +71
    {
        const int p = t & 63, q = t >> 6;
        const float* base = hmp + ((size_t)(bh >> 2) * T32_PER_B + head * 72) * Pn;
        float sp = 0.f;
        #pragma unroll
        for (int jj = 0; jj < 18; ++jj) sp += base[(q + 4 * jj) * Pn + p];
        part[q][p] = sp;
    }
    __syncthreads();
    if (t < Pn) hms[t] = part[0][t] + part[1][t] + part[2][t] + part[3][t];
    __syncthreads();

    // wmsum over this head's group
    float wsum = 0.f;
    for (int i = t; i < Gn; i += 256) wsum += wm[head * Gn + i];
    #pragma unroll
    for (int d = 1; d < 64; d <<= 1) wsum += __shfl_xor(wsum, d);
    if (l == 0) red[wv] = wsum;
    __syncthreads();
    wsum = red[0] + red[1] + red[2] + red[3];

    // logits[c] = sum_k w2[c,k]*hm[k] + b2[c]*wsum
    float lg = 0.f;
    #pragma unroll
    for (int k = 0; k < Pn; ++k) lg = fmaf(w2[t * Pn + k], hms[k], lg);
    lg = fmaf(b2[t], wsum, lg);

    // softmax over 256 channels
    float mx = lg;
    #pragma unroll
    for (int d = 1; d < 64; d <<= 1) mx = fmaxf(mx, __shfl_xor(mx, d));
    __syncthreads();
    if (l == 0) red[wv] = mx;
    __syncthreads();
    mx = fmaxf(fmaxf(red[0], red[1]), fmaxf(red[2], red[3]));
    const float ev = __expf(lg - mx);
    float sm = ev;
    #pragma unroll
    for (int d = 1; d < 64; d <<= 1) sm += __shfl_xor(sm, d);
    __syncthreads();
    if (l == 0) red[wv] = sm;
    __syncthreads();
    sm = red[0] + red[1] + red[2] + red[3];
    masks[t] = ev / sm;
    __syncthreads();

    // wmix[k] = sum_c mask[c]*w2[c,k]
    {
        const int k = t & (Pn - 1);
        const int q = t >> 6;
        float wp = 0.f;
        #pragma unroll
        for (int i = 0; i < 64; ++i) {
            const int c = q * 64 + i;
            wp = fmaf(masks[c], w2[c * Pn + k], wp);
        }
        part[q][k] = wp;
    }
    __syncthreads();
    if (t < Pn) wmix[bh * Pn + t] = part[0][t] + part[1][t] + part[2][t] + part[3][t];

    // bmix = sum_c mask[c]*b2[c]
    float bp = masks[t] * b2[t];
    #pragma unroll
    for (int d = 1; d < 64; d <<= 1) bp += __shfl_xor(bp, d);
    __syncthreads();
    if (l == 0) red[wv] = bp;
    __syncthreads();
    if (t == 0) bmix[bh] = red[0] + red[1] + red[2] + red[3];
}

// ---- K3: pure streaming: ctx[s] = wmix . h[s,:]; out = x + ctx ----
__global__ __launch_bounds__(256)
void k3_stream(const float* __restrict__ x, const short* __restrict__ hg,
               const float* __restrict__ wmix, const float* __restrict__ bmix,
               float* __restrict__ out)
{
    __shared__ float ctxl[STILE];

    const int bid  = blockIdx.x;
    const int b    = bid / TILES_PER_B;
    const int tile = bid % TILES_PER_B;
    const int s0   = tile * STILE;
    const int head = s0 / Gn;
    const int bh   = b * HEADSn + head;
    const int t    = threadIdx.x;

    if (t < STILE) {
        const short* hr = hg + ((size_t)b * HWn + s0 + t) * Pn;   // dense 128 B/lane
        const float* wmx = wmix + bh * Pn;
        float acc = 0.f;
        #pragma unroll
        for (int i = 0; i < 8; ++i) {
            const short8 v = *reinterpret_cast<const short8*>(hr + i * 8);
            const f32x4 w0 = *reinterpret_cast<const f32x4*>(wmx + i * 8);
            const f32x4 w1v = *reinterpret_cast<const f32x4*>(wmx + i * 8 + 4);
            #pragma unroll
            for (int j = 0; j < 4; ++j) {
                acc = fmaf(bf2f((unsigned short)v[j]), w0[j], acc);
                acc = fmaf(bf2f((unsigned short)v[4 + j]), w1v[j], acc);
            }
        }
        ctxl[t] = acc + bmix[bh];
    }
    __syncthreads();

    const int c0 = t >> 4;
    const int s4 = t & 15;
    const f32x4 cv = *reinterpret_cast<const f32x4*>(&ctxl[s4 * 4]);
    const float* xb = x + (size_t)b * Cn * HWn + s0 + s4 * 4;
    float* ob = out + (size_t)b * Cn * HWn + s0 + s4 * 4;
    #pragma unroll
    for (int i = 0; i < 16; ++i) {
        const size_t off = (size_t)(c0 + 16 * i) * HWn;
        *reinterpret_cast<f32x4*>(ob + off) =
            *reinterpret_cast<const f32x4*>(xb + off) + cv;
    }
}

extern "C" void kernel_launch(void* const* d_in, const int* in_sizes, int n_in,
                              void* d_out, int out_size, void* d_ws, size_t ws_size,
                              hipStream_t stream)
{
    (void)in_sizes; (void)n_in; (void)out_size; (void)ws_size;
    const float* x     = (const float*)d_in[0];
    const float* w1    = (const float*)d_in[1];
    const float* b1    = (const float*)d_in[2];
    const float* gamma = (const float*)d_in[3];
    const float* beta  = (const float*)d_in[4];
    const float* mean  = (const float*)d_in[5];
    const float* var   = (const float*)d_in[6];
    const float* w2    = (const float*)d_in[7];
    const float* b2    = (const float*)d_in[8];
    const float* wm    = (const float*)d_in[9];
    // d_in[10] = bm: constant over softmax axis -> dropped

    float* out  = (float*)d_out;
    float* wsf  = (float*)d_ws;
    float* hmp  = wsf;                            // [4608*64] f32 tile partials
    float* wmix = hmp + NBLK1 * Pn;               // [64*64]
    float* bmix = wmix + Bn * HEADSn * Pn;        // [64]
    float* bcv  = bmix + 64;                      // [64]
    short* w1b  = (short*)(bcv + 64);             // [64*256] bf16, BN-scale folded
    short* hg   = w1b + Pn * Cn;                  // [16*9216*64] bf16

    k0_prep<<<dim3(8), dim3(256), 0, stream>>>(w1, b1, gamma, beta, mean, var, bcv, w1b);
    k1_gemm<<<dim3(NBLK1), dim3(128), 0, stream>>>(x, w1b, bcv, wm, hmp, hg);
    k2_mask<<<dim3(Bn * HEADSn), dim3(256), 0, stream>>>(hmp, w2, b2, wm, wmix, bmix);
    k3_stream<<<dim3(NTILE), dim3(256), 0, stream>>>(x, hg, wmix, bmix, out);
}